// Round 4
// baseline (567.156 us; speedup 1.0000x reference)
//
#include <hip/hip_runtime.h>
#include <hip/hip_bf16.h>

#define DIM   4096
#define NH    32
#define HD    128
#define BATCH 2
#define SEQ   1024
#define MROWS (BATCH*SEQ)   // 2048
#define LDQ   12288         // fused qkv row stride

typedef __attribute__((ext_vector_type(8))) short bf16x8;
typedef __attribute__((ext_vector_type(4))) short s16x4;
typedef __attribute__((ext_vector_type(4))) float f32x4;

__device__ inline void gload_lds16(const void* g, void* l) {
  __builtin_amdgcn_global_load_lds(
      (const __attribute__((address_space(1))) void*)g,
      (__attribute__((address_space(3))) void*)l, 16, 0, 0);
}

__device__ inline float bf2f(short b) {
  unsigned u = ((unsigned)(unsigned short)b) << 16;
  return __uint_as_float(u);
}
__device__ inline unsigned short f2bfu(float f) {
  __hip_bfloat16 h = __float2bfloat16(f);
  return *reinterpret_cast<unsigned short*>(&h);
}

// ---------------- fp32 -> bf16 convert (vectorized) ----------------
__global__ void cvt_bf16_kernel(const float* __restrict__ in,
                                unsigned short* __restrict__ out, long n4) {
  long i = blockIdx.x * (long)blockDim.x + threadIdx.x;
  long stride = (long)gridDim.x * blockDim.x;
  for (; i < n4; i += stride) {
    float4 v = ((const float4*)in)[i];
    ushort4 o;
    o.x = f2bfu(v.x); o.y = f2bfu(v.y); o.z = f2bfu(v.z); o.w = f2bfu(v.w);
    ((ushort4*)out)[i] = o;
  }
}

// ---------------- bias concat (bq|bk|bv -> 12288) ----------------
__global__ void concat3_kernel(const float* __restrict__ a, const float* __restrict__ b,
                               const float* __restrict__ c, float* __restrict__ o) {
  int i = blockIdx.x * blockDim.x + threadIdx.x;
  if (i < 4096) o[i] = a[i];
  else if (i < 8192) o[i] = b[i - 4096];
  else if (i < 12288) o[i] = c[i - 8192];
}

// ---------------- RoPE cos/sin table ----------------
__global__ void rope_table_kernel(float* __restrict__ cosT, float* __restrict__ sinT) {
  int s = blockIdx.x;     // 0..SEQ-1
  int p = threadIdx.x;    // 0..63
  float inv = powf(10000.0f, -((float)(2 * p)) / 128.0f);
  float a = (float)s * inv;
  cosT[s * 64 + p] = cosf(a);
  sinT[s * 64 + p] = sinf(a);
}

// ---------------- reduce K-split partials + bias (fp32) ----------------
__global__ void reduce_bias_kernel(const float* __restrict__ part,
                                   const float* __restrict__ bias,
                                   float* __restrict__ out) {
  long i = blockIdx.x * (long)blockDim.x + threadIdx.x;  // float4 index
  if (i >= (long)MROWS * DIM / 4) return;
  float4 a = ((const float4*)part)[i];
  float4 b = ((const float4*)(part + (size_t)MROWS * DIM))[i];
  float4 bb = ((const float4*)bias)[(int)(i & (DIM / 4 - 1))];
  float4 o;
  o.x = a.x + b.x + bb.x; o.y = a.y + b.y + bb.y;
  o.z = a.z + b.z + bb.z; o.w = a.w + b.w + bb.w;
  ((float4*)out)[i] = o;
}

// ---------------- Quadrant-phased GEMM: C = A * B^T (+bias) (+RoPE) ----------
// BM=BN=256, BK=64. 512 threads = 8 waves (2M x 4N); per-wave 128x64 output.
// LDS 128KB double-buffered. Per K-tile: 4 phases, each {frag ds_reads |
// stage gloads -> s_barrier -> setprio(1) -> 16 MFMA -> setprio(0)}.
// Mid-tile lgkmcnt(0)+barrier before overwriting buf[cur] with tile t+2.
// End-of-tile vmcnt(8): tile t+1 landed, t+2's 8 loads in flight (T4).
// XOR swizzle (16B chunk ^ row&7) applied source-side + read-side.
// blockIdx.z = K-split slice (WO GEMM); QKV uses z-dim 1.
__device__ __forceinline__ void stage_half(
    const unsigned short* __restrict__ A, const unsigned short* __restrict__ Bw,
    unsigned short* Asl, unsigned short* Bsl,
    int m0, int n0, size_t Kstr, int kcol0, int t, int half) {
#pragma unroll
  for (int j = 0; j < 2; ++j) {
    int ci = (half * 2 + j) * 512 + t;
    int r = ci >> 3, c = ci & 7;
    gload_lds16(A + (size_t)(m0 + r) * Kstr + kcol0 + ((c ^ (r & 7)) << 3), Asl + ci * 8);
  }
#pragma unroll
  for (int j = 0; j < 2; ++j) {
    int ci = (half * 2 + j) * 512 + t;
    int r = ci >> 3, c = ci & 7;
    gload_lds16(Bw + (size_t)(n0 + r) * Kstr + kcol0 + ((c ^ (r & 7)) << 3), Bsl + ci * 8);
  }
}

template <typename OutT, bool QKV_MODE>
__global__ __launch_bounds__(512, 2) void gemm_q_kernel(
    const unsigned short* __restrict__ A, const unsigned short* __restrict__ Bw,
    const float* __restrict__ bias, OutT* __restrict__ C,
    int M, int N, int Kstr, int Klen,
    const float* __restrict__ cosT, const float* __restrict__ sinT) {
  __shared__ unsigned short As[2][256 * 64];   // 64 KB
  __shared__ unsigned short Bs[2][128 * 64 * 2]; // 64 KB (256 rows x 64)
  const int t = threadIdx.x;
  const int lane = t & 63;
  const int w = t >> 6;
  const int wm = w >> 2, wn = w & 3;           // 2M x 4N wave grid
  const int np = lane & 15, hq = lane >> 4;

  // T1 bijective XCD swizzle over (x,y); grid.x*grid.y % 8 == 0 by construction
  int bid = blockIdx.y * gridDim.x + blockIdx.x;
  int nwg = gridDim.x * gridDim.y;
  int sb = (bid & 7) * (nwg >> 3) + (bid >> 3);
  int bx = sb % gridDim.x, by = sb / gridDim.x;
  const int m0 = by * 256, n0 = bx * 256;
  const int kb0 = blockIdx.z * Klen;
  const int NT = Klen >> 6;
  OutT* Cz = C + (size_t)blockIdx.z * M * N;

  // prologue: stage tiles 0,1
  stage_half(A, Bw, As[0], Bs[0], m0, n0, Kstr, kb0, t, 0);
  stage_half(A, Bw, As[0], Bs[0], m0, n0, Kstr, kb0, t, 1);
  stage_half(A, Bw, As[1], Bs[1], m0, n0, Kstr, kb0 + 64, t, 0);
  stage_half(A, Bw, As[1], Bs[1], m0, n0, Kstr, kb0 + 64, t, 1);

  f32x4 acc[8][4] = {};

  asm volatile("s_waitcnt vmcnt(8)" ::: "memory");   // tile 0 landed
  __builtin_amdgcn_s_barrier();

  int cur = 0;
#pragma unroll 1
  for (int kt = 0; kt < NT; ++kt) {
    const unsigned short* Asl = As[cur];
    const unsigned short* Bsl = Bs[cur];
    bf16x8 af[4][2], bf[4][2];
    const int swz = np & 7;

    // ---- ph0: A rows 0-63, B cols 0-31 frags; MFMA q(0,0) ----
#pragma unroll
    for (int rb = 0; rb < 4; ++rb)
#pragma unroll
      for (int kh = 0; kh < 2; ++kh)
        af[rb][kh] = *(const bf16x8*)&Asl[(wm * 128 + rb * 16 + np) * 64 +
                                          (((kh * 4 + hq) ^ swz) << 3)];
#pragma unroll
    for (int cb = 0; cb < 2; ++cb)
#pragma unroll
      for (int kh = 0; kh < 2; ++kh)
        bf[cb][kh] = *(const bf16x8*)&Bsl[(wn * 64 + cb * 16 + np) * 64 +
                                          (((kh * 4 + hq) ^ swz) << 3)];
    __builtin_amdgcn_s_barrier();
    __builtin_amdgcn_s_setprio(1);
#pragma unroll
    for (int i = 0; i < 4; ++i)
#pragma unroll
      for (int j = 0; j < 2; ++j) {
        acc[i][j] = __builtin_amdgcn_mfma_f32_16x16x32_bf16(af[i][0], bf[j][0], acc[i][j], 0, 0, 0);
        acc[i][j] = __builtin_amdgcn_mfma_f32_16x16x32_bf16(af[i][1], bf[j][1], acc[i][j], 0, 0, 0);
      }
    __builtin_amdgcn_s_setprio(0);

    // ---- ph1: B cols 32-63 frags; MFMA q(0,1) ----
#pragma unroll
    for (int cb = 2; cb < 4; ++cb)
#pragma unroll
      for (int kh = 0; kh < 2; ++kh)
        bf[cb][kh] = *(const bf16x8*)&Bsl[(wn * 64 + cb * 16 + np) * 64 +
                                          (((kh * 4 + hq) ^ swz) << 3)];
    __builtin_amdgcn_s_barrier();
    __builtin_amdgcn_s_setprio(1);
#pragma unroll
    for (int i = 0; i < 4; ++i)
#pragma unroll
      for (int j = 0; j < 2; ++j) {
        acc[i][j + 2] = __builtin_amdgcn_mfma_f32_16x16x32_bf16(af[i][0], bf[j + 2][0], acc[i][j + 2], 0, 0, 0);
        acc[i][j + 2] = __builtin_amdgcn_mfma_f32_16x16x32_bf16(af[i][1], bf[j + 2][1], acc[i][j + 2], 0, 0, 0);
      }
    __builtin_amdgcn_s_setprio(0);

    // ---- ph2: A rows 64-127 frags; all buf[cur] reads done -> stage t+2 ----
#pragma unroll
    for (int rb = 0; rb < 4; ++rb)
#pragma unroll
      for (int kh = 0; kh < 2; ++kh)
        af[rb][kh] = *(const bf16x8*)&Asl[(wm * 128 + 64 + rb * 16 + np) * 64 +
                                          (((kh * 4 + hq) ^ swz) << 3)];
    asm volatile("s_waitcnt lgkmcnt(0)" ::: "memory");
    __builtin_amdgcn_sched_barrier(0);
    __builtin_amdgcn_s_barrier();
    if (kt + 2 < NT)
      stage_half(A, Bw, As[cur], Bs[cur], m0, n0, Kstr, kb0 + ((kt + 2) << 6), t, 0);
    __builtin_amdgcn_s_setprio(1);
#pragma unroll
    for (int i = 0; i < 4; ++i)
#pragma unroll
      for (int j = 0; j < 2; ++j) {
        acc[i + 4][j] = __builtin_amdgcn_mfma_f32_16x16x32_bf16(af[i][0], bf[j][0], acc[i + 4][j], 0, 0, 0);
        acc[i + 4][j] = __builtin_amdgcn_mfma_f32_16x16x32_bf16(af[i][1], bf[j][1], acc[i + 4][j], 0, 0, 0);
      }
    __builtin_amdgcn_s_setprio(0);

    // ---- ph3: stage rest of t+2; MFMA q(1,1); counted vmcnt ----
    if (kt + 2 < NT)
      stage_half(A, Bw, As[cur], Bs[cur], m0, n0, Kstr, kb0 + ((kt + 2) << 6), t, 1);
    __builtin_amdgcn_s_barrier();
    __builtin_amdgcn_s_setprio(1);
#pragma unroll
    for (int i = 0; i < 4; ++i)
#pragma unroll
      for (int j = 0; j < 2; ++j) {
        acc[i + 4][j + 2] = __builtin_amdgcn_mfma_f32_16x16x32_bf16(af[i][0], bf[j + 2][0], acc[i + 4][j + 2], 0, 0, 0);
        acc[i + 4][j + 2] = __builtin_amdgcn_mfma_f32_16x16x32_bf16(af[i][1], bf[j + 2][1], acc[i + 4][j + 2], 0, 0, 0);
      }
    __builtin_amdgcn_s_setprio(0);
    if (kt + 2 < NT) {
      asm volatile("s_waitcnt vmcnt(8)" ::: "memory");   // t+1 landed; t+2 in flight
    } else {
      asm volatile("s_waitcnt vmcnt(0)" ::: "memory");
    }
    __builtin_amdgcn_s_barrier();
    cur ^= 1;
  }

  // ---- epilogue: bias (+RoPE for QKV cols<8192) + store ----
  const int orow0 = m0 + wm * 128;
  const int ocol0 = n0 + wn * 64 + np;
  const bool do_rope = QKV_MODE && (n0 < 8192);
#pragma unroll
  for (int j = 0; j < 4; ++j) {
    const int col = ocol0 + j * 16;
    float bj = QKV_MODE ? bias[col] : 0.0f;
    const int p0 = (col & 127) >> 1;
    const bool even = (lane & 1) == 0;
#pragma unroll
    for (int i = 0; i < 8; ++i) {
#pragma unroll
      for (int r = 0; r < 4; ++r) {
        int orow = orow0 + i * 16 + hq * 4 + r;
        float v = acc[i][j][r] + bj;
        if (do_rope) {
          int srow = orow & (SEQ - 1);
          float c = cosT[srow * 64 + p0];
          float s = sinT[srow * 64 + p0];
          float pv = __shfl_xor(v, 1);
          v = even ? (v * c - pv * s) : (pv * s + v * c);
        }
        size_t off = (size_t)orow * N + col;
        if constexpr (sizeof(OutT) == 2)
          ((unsigned short*)Cz)[off] = f2bfu(v);
        else
          ((float*)Cz)[off] = v;
      }
    }
  }
}

// ---------------- Flash attention (causal), reads fused qkv (stride LDQ) -------
__global__ __launch_bounds__(256, 1) void flash_attn_kernel(
    const unsigned short* __restrict__ QKV, unsigned short* __restrict__ O) {
  __shared__ unsigned short Ks[64 * 128];    // swizzled row-major
  __shared__ unsigned short Vt[128 * 64];    // transposed + swizzled
  __shared__ unsigned short Ps[4][32 * 64];  // per-wave P, swizzled

  const int p  = blockIdx.x;   // pair 0..3
  const int bh = blockIdx.y;   // b*NH + h
  const int b  = bh >> 5;
  const int hh = bh & 31;
  const int t    = threadIdx.x;
  const int lane = t & 63;
  const int w    = t >> 6;
  const int np   = lane & 15;
  const int hq   = lane >> 4;

  const size_t rowbase = (size_t)b * SEQ * LDQ;
  const unsigned short* Qg = QKV + rowbase + (size_t)hh * HD;
  const unsigned short* Kg = QKV + rowbase + 4096 + (size_t)hh * HD;
  const unsigned short* Vg = QKV + rowbase + 8192 + (size_t)hh * HD;
  unsigned short* Og = O + (size_t)b * SEQ * DIM + (size_t)hh * HD;

  const int krow = t >> 2;
  const int kc0  = (t & 3) * 32;
  const int vr0  = (t & 15) * 4;
  const int vc0  = (t >> 4) * 8;

  unsigned short* Pw = &Ps[w][0];
  const float SCALE = 0.08838834764831843f;  // 1/sqrt(128)

  bf16x8 vk[4], vv[4];

#pragma unroll 1
  for (int pass = 0; pass < 2; ++pass) {
    const int qt    = pass ? (7 - p) : p;
    const int nt    = 2 * qt + 2;
    const int qbase = qt * 128 + w * 32;

    bf16x8 qf[2][4];
#pragma unroll
    for (int rb = 0; rb < 2; ++rb)
#pragma unroll
      for (int kb = 0; kb < 4; ++kb)
        qf[rb][kb] = *(const bf16x8*)&Qg[(size_t)(qbase + rb * 16 + np) * LDQ + kb * 32 + hq * 8];

    f32x4 acc[2][8] = {};
    float m_run[2][4], l_run[2][4];
#pragma unroll
    for (int rb = 0; rb < 2; ++rb)
#pragma unroll
      for (int r = 0; r < 4; ++r) { m_run[rb][r] = -3.0e38f; l_run[rb][r] = 0.0f; }

    {
      const unsigned short* kp = Kg + (size_t)krow * LDQ + kc0;
      const unsigned short* vp = Vg + (size_t)vr0 * LDQ + vc0;
#pragma unroll
      for (int jj = 0; jj < 4; ++jj) vk[jj] = *(const bf16x8*)(kp + jj * 8);
#pragma unroll
      for (int jj = 0; jj < 4; ++jj) vv[jj] = *(const bf16x8*)(vp + (size_t)jj * LDQ);
    }

#pragma unroll 1
    for (int kt = 0; kt < nt; ++kt) {
      __syncthreads();

#pragma unroll
      for (int jj = 0; jj < 4; ++jj) {
        int c = (t & 3) * 4 + jj;
        *(bf16x8*)((char*)Ks + krow * 256 + ((c ^ (krow & 7)) << 4)) = vk[jj];
      }
#pragma unroll
      for (int i = 0; i < 8; ++i) {
        int col = vc0 + i;
        s16x4 sv;
        sv[0] = vv[0][i]; sv[1] = vv[1][i]; sv[2] = vv[2][i]; sv[3] = vv[3][i];
        *(s16x4*)((char*)Vt + ((col * 128 + vr0 * 2) ^ ((col & 7) << 4))) = sv;
      }
      __syncthreads();

      if (kt + 1 < nt) {
        const unsigned short* kp = Kg + (size_t)((kt + 1) * 64 + krow) * LDQ + kc0;
        const unsigned short* vp = Vg + (size_t)((kt + 1) * 64 + vr0) * LDQ + vc0;
#pragma unroll
        for (int jj = 0; jj < 4; ++jj) vk[jj] = *(const bf16x8*)(kp + jj * 8);
#pragma unroll
        for (int jj = 0; jj < 4; ++jj) vv[jj] = *(const bf16x8*)(vp + (size_t)jj * LDQ);
      }

      f32x4 sc[4][2] = {};
#pragma unroll
      for (int ct = 0; ct < 4; ++ct) {
#pragma unroll
        for (int kb = 0; kb < 4; ++kb) {
          bf16x8 kf = *(const bf16x8*)((char*)Ks + (ct * 16 + np) * 256 +
                                       (((kb * 4 + hq) ^ (np & 7)) << 4));
          sc[ct][0] = __builtin_amdgcn_mfma_f32_16x16x32_bf16(qf[0][kb], kf, sc[ct][0], 0, 0, 0);
          sc[ct][1] = __builtin_amdgcn_mfma_f32_16x16x32_bf16(qf[1][kb], kf, sc[ct][1], 0, 0, 0);
        }
      }

      const bool maskt = (kt >= 2 * qt);
#pragma unroll
      for (int ct = 0; ct < 4; ++ct) {
        int kvc = kt * 64 + ct * 16 + np;
#pragma unroll
        for (int rb = 0; rb < 2; ++rb)
#pragma unroll
          for (int r = 0; r < 4; ++r) {
            float v = sc[ct][rb][r] * SCALE;
            if (maskt && kvc > qbase + rb * 16 + hq * 4 + r) v = -1.0e9f;
            sc[ct][rb][r] = v;
          }
      }

      float sf[2][4];
#pragma unroll
      for (int rb = 0; rb < 2; ++rb)
#pragma unroll
        for (int r = 0; r < 4; ++r) {
          float tmax = fmaxf(fmaxf(sc[0][rb][r], sc[1][rb][r]),
                             fmaxf(sc[2][rb][r], sc[3][rb][r]));
          tmax = fmaxf(tmax, __shfl_xor(tmax, 1));
          tmax = fmaxf(tmax, __shfl_xor(tmax, 2));
          tmax = fmaxf(tmax, __shfl_xor(tmax, 4));
          tmax = fmaxf(tmax, __shfl_xor(tmax, 8));
          float mn = fmaxf(m_run[rb][r], tmax);
          sf[rb][r] = __expf(m_run[rb][r] - mn);
          m_run[rb][r] = mn;
        }

#pragma unroll
      for (int rb = 0; rb < 2; ++rb)
#pragma unroll
        for (int r = 0; r < 4; ++r) {
          int prow = rb * 16 + hq * 4 + r;
          int swz = (prow & 7) << 4;
          float rsum = 0.f;
#pragma unroll
          for (int ct = 0; ct < 4; ++ct) {
            float pv = __expf(sc[ct][rb][r] - m_run[rb][r]);
            rsum += pv;
            *(unsigned short*)((char*)Pw + ((prow * 128 + (ct * 16 + np) * 2) ^ swz)) = f2bfu(pv);
          }
          rsum += __shfl_xor(rsum, 1);
          rsum += __shfl_xor(rsum, 2);
          rsum += __shfl_xor(rsum, 4);
          rsum += __shfl_xor(rsum, 8);
          l_run[rb][r] = l_run[rb][r] * sf[rb][r] + rsum;
        }

#pragma unroll
      for (int rb = 0; rb < 2; ++rb)
#pragma unroll
        for (int nt2 = 0; nt2 < 8; ++nt2)
#pragma unroll
          for (int r = 0; r < 4; ++r)
            acc[rb][nt2][r] *= sf[rb][r];

#pragma unroll
      for (int kb2 = 0; kb2 < 2; ++kb2) {
        bf16x8 pa0 = *(const bf16x8*)((char*)Pw +
            (((0 * 16 + np) * 128 + kb2 * 64 + hq * 16) ^ ((np & 7) << 4)));
        bf16x8 pa1 = *(const bf16x8*)((char*)Pw +
            (((1 * 16 + np) * 128 + kb2 * 64 + hq * 16) ^ ((np & 7) << 4)));
#pragma unroll
        for (int nt2 = 0; nt2 < 8; ++nt2) {
          int col = nt2 * 16 + np;
          bf16x8 vf = *(const bf16x8*)((char*)Vt +
              ((col * 128 + kb2 * 64 + hq * 16) ^ ((col & 7) << 4)));
          acc[0][nt2] = __builtin_amdgcn_mfma_f32_16x16x32_bf16(pa0, vf, acc[0][nt2], 0, 0, 0);
          acc[1][nt2] = __builtin_amdgcn_mfma_f32_16x16x32_bf16(pa1, vf, acc[1][nt2], 0, 0, 0);
        }
      }
    }

#pragma unroll
    for (int rb = 0; rb < 2; ++rb)
#pragma unroll
      for (int r = 0; r < 4; ++r) {
        float rl = 1.0f / l_run[rb][r];
        int orow = qbase + rb * 16 + hq * 4 + r;
#pragma unroll
        for (int nt2 = 0; nt2 < 8; ++nt2)
          Og[(size_t)orow * DIM + nt2 * 16 + np] = f2bfu(acc[rb][nt2][r] * rl);
      }
  }
}

extern "C" void kernel_launch(void* const* d_in, const int* in_sizes, int n_in,
                              void* d_out, int out_size, void* d_ws, size_t ws_size,
                              hipStream_t stream) {
  const float* x  = (const float*)d_in[0];
  const float* wq = (const float*)d_in[1];
  const float* bq = (const float*)d_in[2];
  const float* wk = (const float*)d_in[3];
  const float* bk = (const float*)d_in[4];
  const float* wv = (const float*)d_in[5];
  const float* bv = (const float*)d_in[6];
  const float* wo = (const float*)d_in[7];
  const float* bo = (const float*)d_in[8];
  float* out = (float*)d_out;

  char* ws = (char*)d_ws;
  unsigned short* wqkvb = (unsigned short*)(ws);                  // 96 MB [12288][4096]
  float* part           = (float*)(ws);                           // 64 MB (overlays wqkvb; used after QKV GEMM done)
  unsigned short* wob   = (unsigned short*)(ws + (96ll  << 20));  // 32 MB
  unsigned short* xb    = (unsigned short*)(ws + (128ll << 20));  // 16 MB
  unsigned short* qkv   = (unsigned short*)(ws + (144ll << 20));  // 48 MB [2048][12288]
  unsigned short* ab    = (unsigned short*)(ws + (192ll << 20));  // 16 MB
  float* biasqkv = (float*)(ws + (208ll << 20));                  // 48 KB
  float* cosT    = (float*)(ws + (208ll << 20) + (64  << 10));    // 256 KB
  float* sinT    = (float*)(ws + (208ll << 20) + (320 << 10));    // 256 KB

  // fp32 -> bf16 (weights packed: wq|wk|wv contiguous rows)
  cvt_bf16_kernel<<<2048, 256, 0, stream>>>(x,  xb, (long)MROWS * DIM / 4);
  cvt_bf16_kernel<<<2048, 256, 0, stream>>>(wq, wqkvb,                        (long)DIM * DIM / 4);
  cvt_bf16_kernel<<<2048, 256, 0, stream>>>(wk, wqkvb + (size_t)DIM * DIM,    (long)DIM * DIM / 4);
  cvt_bf16_kernel<<<2048, 256, 0, stream>>>(wv, wqkvb + 2 * (size_t)DIM * DIM,(long)DIM * DIM / 4);
  cvt_bf16_kernel<<<2048, 256, 0, stream>>>(wo, wob, (long)DIM * DIM / 4);

  concat3_kernel<<<48, 256, 0, stream>>>(bq, bk, bv, biasqkv);
  rope_table_kernel<<<SEQ, 64, 0, stream>>>(cosT, sinT);

  // fused QKV GEMM (+bias +RoPE in epilogue): [2048,4096]x[12288,4096]^T
  dim3 gq(LDQ / 256, MROWS / 256, 1);  // (48, 8) = 384 blocks
  gemm_q_kernel<unsigned short, true><<<gq, 512, 0, stream>>>(
      xb, wqkvb, biasqkv, qkv, MROWS, LDQ, DIM, DIM, cosT, sinT);

  dim3 ga(4, BATCH * NH);  // 4 qtile-pairs x 64 heads
  flash_attn_kernel<<<ga, 256, 0, stream>>>(qkv, ab);

  // output GEMM, K-split x2 into fp32 partials (overlaying dead wqkvb region)
  dim3 go(DIM / 256, MROWS / 256, 2);  // (16, 8, 2) = 256 blocks
  gemm_q_kernel<float, false><<<go, 512, 0, stream>>>(
      ab, wob, nullptr, part, MROWS, DIM, DIM, DIM / 2, nullptr, nullptr);

  reduce_bias_kernel<<<(MROWS * DIM / 4 + 255) / 256, 256, 0, stream>>>(part, bo, out);
}

// Round 5
// 529.198 us; speedup vs baseline: 1.0717x; 1.0717x over previous
//
#include <hip/hip_runtime.h>
#include <hip/hip_bf16.h>

#define DIM   4096
#define NH    32
#define HD    128
#define BATCH 2
#define SEQ   1024
#define MROWS (BATCH*SEQ)   // 2048
#define LDQ   12288         // fused qkv row stride

typedef __attribute__((ext_vector_type(8))) short bf16x8;
typedef __attribute__((ext_vector_type(4))) short s16x4;
typedef __attribute__((ext_vector_type(4))) float f32x4;

__device__ inline void gload_lds16(const void* g, void* l) {
  __builtin_amdgcn_global_load_lds(
      (const __attribute__((address_space(1))) void*)g,
      (__attribute__((address_space(3))) void*)l, 16, 0, 0);
}

__device__ inline float bf2f(short b) {
  unsigned u = ((unsigned)(unsigned short)b) << 16;
  return __uint_as_float(u);
}
__device__ inline unsigned short f2bfu(float f) {
  __hip_bfloat16 h = __float2bfloat16(f);
  return *reinterpret_cast<unsigned short*>(&h);
}

template <int N> __device__ __forceinline__ void wait_vm() {
  if constexpr (N == 0)      asm volatile("s_waitcnt vmcnt(0)" ::: "memory");
  else if constexpr (N == 7) asm volatile("s_waitcnt vmcnt(7)" ::: "memory");
  else                       asm volatile("s_waitcnt vmcnt(8)" ::: "memory");
}

// ---------------- fp32 -> bf16 convert (vectorized) ----------------
__global__ void cvt_bf16_kernel(const float* __restrict__ in,
                                unsigned short* __restrict__ out, long n4) {
  long i = blockIdx.x * (long)blockDim.x + threadIdx.x;
  long stride = (long)gridDim.x * blockDim.x;
  for (; i < n4; i += stride) {
    float4 v = ((const float4*)in)[i];
    ushort4 o;
    o.x = f2bfu(v.x); o.y = f2bfu(v.y); o.z = f2bfu(v.z); o.w = f2bfu(v.w);
    ((ushort4*)out)[i] = o;
  }
}

// ---------------- bias concat (bq|bk|bv -> 12288) ----------------
__global__ void concat3_kernel(const float* __restrict__ a, const float* __restrict__ b,
                               const float* __restrict__ c, float* __restrict__ o) {
  int i = blockIdx.x * blockDim.x + threadIdx.x;
  if (i < 4096) o[i] = a[i];
  else if (i < 8192) o[i] = b[i - 4096];
  else if (i < 12288) o[i] = c[i - 8192];
}

// ---------------- RoPE cos/sin table ----------------
__global__ void rope_table_kernel(float* __restrict__ cosT, float* __restrict__ sinT) {
  int s = blockIdx.x;     // 0..SEQ-1
  int p = threadIdx.x;    // 0..63
  float inv = powf(10000.0f, -((float)(2 * p)) / 128.0f);
  float a = (float)s * inv;
  cosT[s * 64 + p] = cosf(a);
  sinT[s * 64 + p] = sinf(a);
}

// ---------------- reduce K-split partials + bias (fp32) ----------------
__global__ void reduce_bias_kernel(const float* __restrict__ part,
                                   const float* __restrict__ bias,
                                   float* __restrict__ out) {
  long i = blockIdx.x * (long)blockDim.x + threadIdx.x;  // float4 index
  if (i >= (long)MROWS * DIM / 4) return;
  float4 a = ((const float4*)part)[i];
  float4 b = ((const float4*)(part + (size_t)MROWS * DIM))[i];
  float4 bb = ((const float4*)bias)[(int)(i & (DIM / 4 - 1))];
  float4 o;
  o.x = a.x + b.x + bb.x; o.y = a.y + b.y + bb.y;
  o.z = a.z + b.z + bb.z; o.w = a.w + b.w + bb.w;
  ((float4*)out)[i] = o;
}

// ---------------- Phased GEMM: C = A * B^T (+bias) (+RoPE) --------------------
// BM=256, BN=NB (192 QKV / 256 WO), BK=64. 512 threads = 8 waves (2M x 4N).
// Per K-tile 4 phases: all frag ds_reads in ph0/ph1 (lgkm drain at ph1), stage
// gloads spread 2/2/BL across ph1-3, one counted vmcnt per tile (never drain).
// XOR swizzle (16B chunk ^ row&7) source-side + read-side.
template <typename OutT, bool QKV_MODE, int NB>
__global__ __launch_bounds__(512, 2) void gemm_q_kernel(
    const unsigned short* __restrict__ A, const unsigned short* __restrict__ Bw,
    const float* __restrict__ bias, OutT* __restrict__ C,
    int M, int N, int Kstr, int Klen,
    const float* __restrict__ cosT, const float* __restrict__ sinT) {
  constexpr int CBF = NB / 64;   // B frags per wave (3 or 4)
  constexpr int BL  = NB / 64;   // B gloads per thread per tile
  constexpr int VM  = 4 + BL;    // total gloads per tile
  constexpr int WNC = NB / 4;    // per-wave col span
  __shared__ unsigned short As[2][256 * 64];
  __shared__ unsigned short Bs[2][NB * 64];
  const int t = threadIdx.x;
  const int lane = t & 63;
  const int w = t >> 6;
  const int wm = w >> 2, wn = w & 3;
  const int np = lane & 15, hq = lane >> 4;

  // T1 bijective XCD swizzle; grid.x*grid.y % 8 == 0 by construction
  int bid = blockIdx.y * gridDim.x + blockIdx.x;
  int nwg = gridDim.x * gridDim.y;
  int sb = (bid & 7) * (nwg >> 3) + (bid >> 3);
  int bx = sb % gridDim.x, by = sb / gridDim.x;
  const int m0 = by * 256, n0 = bx * NB;
  const int kb0 = blockIdx.z * Klen;
  const int NT = Klen >> 6;
  OutT* Cz = C + (size_t)blockIdx.z * M * N;

  auto stageA2 = [&](unsigned short* Asl, int kcol0, int j0) {
#pragma unroll
    for (int j = j0; j < j0 + 2; ++j) {
      int ci = j * 512 + t;
      int r = ci >> 3, c = ci & 7;
      gload_lds16(A + (size_t)(m0 + r) * Kstr + kcol0 + ((c ^ (r & 7)) << 3), Asl + ci * 8);
    }
  };
  auto stageB = [&](unsigned short* Bsl, int kcol0) {
#pragma unroll
    for (int j = 0; j < BL; ++j) {
      int ci = j * 512 + t;
      int r = ci >> 3, c = ci & 7;
      gload_lds16(Bw + (size_t)(n0 + r) * Kstr + kcol0 + ((c ^ (r & 7)) << 3), Bsl + ci * 8);
    }
  };

  // prologue: stage tiles 0 and 1
  stageA2(As[0], kb0, 0); stageA2(As[0], kb0, 2); stageB(Bs[0], kb0);
  stageA2(As[1], kb0 + 64, 0); stageA2(As[1], kb0 + 64, 2); stageB(Bs[1], kb0 + 64);

  f32x4 acc[8][CBF] = {};

  wait_vm<VM>();                 // tile 0 landed
  __builtin_amdgcn_s_barrier();

  int cur = 0;
#pragma unroll 1
  for (int kt = 0; kt < NT; ++kt) {
    const unsigned short* Asl = As[cur];
    const unsigned short* Bsl = Bs[cur];
    const int swz = np & 7;
    const int kn = kb0 + ((kt + 2) << 6);
    const bool more = (kt + 2 < NT);
    bf16x8 al[4][2], ah[4][2], bf[CBF][2];

    // ---- ph0: A-low + all B frag reads; MFMA A-low x B[0,1] ----
#pragma unroll
    for (int rb = 0; rb < 4; ++rb)
#pragma unroll
      for (int kh = 0; kh < 2; ++kh)
        al[rb][kh] = *(const bf16x8*)&Asl[(wm * 128 + rb * 16 + np) * 64 +
                                          (((kh * 4 + hq) ^ swz) << 3)];
#pragma unroll
    for (int cb = 0; cb < CBF; ++cb)
#pragma unroll
      for (int kh = 0; kh < 2; ++kh)
        bf[cb][kh] = *(const bf16x8*)&Bsl[(wn * WNC + cb * 16 + np) * 64 +
                                          (((kh * 4 + hq) ^ swz) << 3)];
    __builtin_amdgcn_s_barrier();
    __builtin_amdgcn_s_setprio(1);
#pragma unroll
    for (int i = 0; i < 4; ++i)
#pragma unroll
      for (int j = 0; j < 2; ++j) {
        acc[i][j] = __builtin_amdgcn_mfma_f32_16x16x32_bf16(al[i][0], bf[j][0], acc[i][j], 0, 0, 0);
        acc[i][j] = __builtin_amdgcn_mfma_f32_16x16x32_bf16(al[i][1], bf[j][1], acc[i][j], 0, 0, 0);
      }
    __builtin_amdgcn_s_setprio(0);

    // ---- ph1: A-high reads; drain; stage A pair 0; MFMA A-low x B[2..] ----
#pragma unroll
    for (int rb = 0; rb < 4; ++rb)
#pragma unroll
      for (int kh = 0; kh < 2; ++kh)
        ah[rb][kh] = *(const bf16x8*)&Asl[(wm * 128 + 64 + rb * 16 + np) * 64 +
                                          (((kh * 4 + hq) ^ swz) << 3)];
    asm volatile("s_waitcnt lgkmcnt(0)" ::: "memory");  // all my buf[cur] reads done
    __builtin_amdgcn_sched_barrier(0);
    __builtin_amdgcn_s_barrier();                        // everyone's reads done
    if (more) stageA2(As[cur], kn, 0);
    __builtin_amdgcn_s_setprio(1);
#pragma unroll
    for (int i = 0; i < 4; ++i)
#pragma unroll
      for (int j = 2; j < CBF; ++j) {
        acc[i][j] = __builtin_amdgcn_mfma_f32_16x16x32_bf16(al[i][0], bf[j][0], acc[i][j], 0, 0, 0);
        acc[i][j] = __builtin_amdgcn_mfma_f32_16x16x32_bf16(al[i][1], bf[j][1], acc[i][j], 0, 0, 0);
      }
    __builtin_amdgcn_s_setprio(0);
    __builtin_amdgcn_s_barrier();

    // ---- ph2: stage A pair 1; MFMA A-high x B[0,1] ----
    if (more) stageA2(As[cur], kn, 2);
    __builtin_amdgcn_s_setprio(1);
#pragma unroll
    for (int i = 0; i < 4; ++i)
#pragma unroll
      for (int j = 0; j < 2; ++j) {
        acc[i + 4][j] = __builtin_amdgcn_mfma_f32_16x16x32_bf16(ah[i][0], bf[j][0], acc[i + 4][j], 0, 0, 0);
        acc[i + 4][j] = __builtin_amdgcn_mfma_f32_16x16x32_bf16(ah[i][1], bf[j][1], acc[i + 4][j], 0, 0, 0);
      }
    __builtin_amdgcn_s_setprio(0);
    __builtin_amdgcn_s_barrier();

    // ---- ph3: stage B; MFMA A-high x B[2..]; counted vmcnt ----
    if (more) stageB(Bs[cur], kn);
    __builtin_amdgcn_s_setprio(1);
#pragma unroll
    for (int i = 0; i < 4; ++i)
#pragma unroll
      for (int j = 2; j < CBF; ++j) {
        acc[i + 4][j] = __builtin_amdgcn_mfma_f32_16x16x32_bf16(ah[i][0], bf[j][0], acc[i + 4][j], 0, 0, 0);
        acc[i + 4][j] = __builtin_amdgcn_mfma_f32_16x16x32_bf16(ah[i][1], bf[j][1], acc[i + 4][j], 0, 0, 0);
      }
    __builtin_amdgcn_s_setprio(0);
    if (more) wait_vm<VM>();      // t+1 landed; t+2 stays in flight
    else      wait_vm<0>();
    __builtin_amdgcn_s_barrier();
    cur ^= 1;
  }

  // ---- epilogue: bias (+RoPE for QKV cols<8192) + store ----
  const int orow0 = m0 + wm * 128;
  const int ocol0 = n0 + wn * WNC + np;
#pragma unroll
  for (int j = 0; j < CBF; ++j) {
    const int col = ocol0 + j * 16;
    float bj = QKV_MODE ? bias[col] : 0.0f;
    const int p0 = (col & 127) >> 1;
    const bool even = (lane & 1) == 0;
    const bool do_rope = QKV_MODE && (col < 8192);
#pragma unroll
    for (int i = 0; i < 8; ++i) {
#pragma unroll
      for (int r = 0; r < 4; ++r) {
        int orow = orow0 + i * 16 + hq * 4 + r;
        float v = acc[i][j][r] + bj;
        float pv = __shfl_xor(v, 1);
        if (do_rope) {
          int srow = orow & (SEQ - 1);
          float c = cosT[srow * 64 + p0];
          float s = sinT[srow * 64 + p0];
          v = even ? (v * c - pv * s) : (pv * s + v * c);
        }
        size_t off = (size_t)orow * N + col;
        if constexpr (sizeof(OutT) == 2)
          ((unsigned short*)Cz)[off] = f2bfu(v);
        else
          ((float*)Cz)[off] = v;
      }
    }
  }
}

// ---------------- Flash attention (causal), reads fused qkv (stride LDQ) -------
__global__ __launch_bounds__(256, 1) void flash_attn_kernel(
    const unsigned short* __restrict__ QKV, unsigned short* __restrict__ O) {
  __shared__ unsigned short Ks[64 * 128];    // swizzled row-major
  __shared__ unsigned short Vt[128 * 64];    // transposed + swizzled
  __shared__ unsigned short Ps[4][32 * 64];  // per-wave P, swizzled

  const int p  = blockIdx.x;   // pair 0..3
  const int bh = blockIdx.y;   // b*NH + h
  const int b  = bh >> 5;
  const int hh = bh & 31;
  const int t    = threadIdx.x;
  const int lane = t & 63;
  const int w    = t >> 6;
  const int np   = lane & 15;
  const int hq   = lane >> 4;

  const size_t rowbase = (size_t)b * SEQ * LDQ;
  const unsigned short* Qg = QKV + rowbase + (size_t)hh * HD;
  const unsigned short* Kg = QKV + rowbase + 4096 + (size_t)hh * HD;
  const unsigned short* Vg = QKV + rowbase + 8192 + (size_t)hh * HD;
  unsigned short* Og = O + (size_t)b * SEQ * DIM + (size_t)hh * HD;

  const int krow = t >> 2;
  const int kc0  = (t & 3) * 32;
  const int vr0  = (t & 15) * 4;
  const int vc0  = (t >> 4) * 8;

  unsigned short* Pw = &Ps[w][0];
  const float SCALE = 0.08838834764831843f;  // 1/sqrt(128)

  bf16x8 vk[4], vv[4];

#pragma unroll 1
  for (int pass = 0; pass < 2; ++pass) {
    const int qt    = pass ? (7 - p) : p;
    const int nt    = 2 * qt + 2;
    const int qbase = qt * 128 + w * 32;

    bf16x8 qf[2][4];
#pragma unroll
    for (int rb = 0; rb < 2; ++rb)
#pragma unroll
      for (int kb = 0; kb < 4; ++kb)
        qf[rb][kb] = *(const bf16x8*)&Qg[(size_t)(qbase + rb * 16 + np) * LDQ + kb * 32 + hq * 8];

    f32x4 acc[2][8] = {};
    float m_run[2][4], l_run[2][4];
#pragma unroll
    for (int rb = 0; rb < 2; ++rb)
#pragma unroll
      for (int r = 0; r < 4; ++r) { m_run[rb][r] = -3.0e38f; l_run[rb][r] = 0.0f; }

    {
      const unsigned short* kp = Kg + (size_t)krow * LDQ + kc0;
      const unsigned short* vp = Vg + (size_t)vr0 * LDQ + vc0;
#pragma unroll
      for (int jj = 0; jj < 4; ++jj) vk[jj] = *(const bf16x8*)(kp + jj * 8);
#pragma unroll
      for (int jj = 0; jj < 4; ++jj) vv[jj] = *(const bf16x8*)(vp + (size_t)jj * LDQ);
    }

#pragma unroll 1
    for (int kt = 0; kt < nt; ++kt) {
      __syncthreads();

#pragma unroll
      for (int jj = 0; jj < 4; ++jj) {
        int c = (t & 3) * 4 + jj;
        *(bf16x8*)((char*)Ks + krow * 256 + ((c ^ (krow & 7)) << 4)) = vk[jj];
      }
#pragma unroll
      for (int i = 0; i < 8; ++i) {
        int col = vc0 + i;
        s16x4 sv;
        sv[0] = vv[0][i]; sv[1] = vv[1][i]; sv[2] = vv[2][i]; sv[3] = vv[3][i];
        *(s16x4*)((char*)Vt + ((col * 128 + vr0 * 2) ^ ((col & 7) << 4))) = sv;
      }
      __syncthreads();

      if (kt + 1 < nt) {
        const unsigned short* kp = Kg + (size_t)((kt + 1) * 64 + krow) * LDQ + kc0;
        const unsigned short* vp = Vg + (size_t)((kt + 1) * 64 + vr0) * LDQ + vc0;
#pragma unroll
        for (int jj = 0; jj < 4; ++jj) vk[jj] = *(const bf16x8*)(kp + jj * 8);
#pragma unroll
        for (int jj = 0; jj < 4; ++jj) vv[jj] = *(const bf16x8*)(vp + (size_t)jj * LDQ);
      }

      f32x4 sc[4][2] = {};
#pragma unroll
      for (int ct = 0; ct < 4; ++ct) {
#pragma unroll
        for (int kb = 0; kb < 4; ++kb) {
          bf16x8 kf = *(const bf16x8*)((char*)Ks + (ct * 16 + np) * 256 +
                                       (((kb * 4 + hq) ^ (np & 7)) << 4));
          sc[ct][0] = __builtin_amdgcn_mfma_f32_16x16x32_bf16(qf[0][kb], kf, sc[ct][0], 0, 0, 0);
          sc[ct][1] = __builtin_amdgcn_mfma_f32_16x16x32_bf16(qf[1][kb], kf, sc[ct][1], 0, 0, 0);
        }
      }

      const bool maskt = (kt >= 2 * qt);
#pragma unroll
      for (int ct = 0; ct < 4; ++ct) {
        int kvc = kt * 64 + ct * 16 + np;
#pragma unroll
        for (int rb = 0; rb < 2; ++rb)
#pragma unroll
          for (int r = 0; r < 4; ++r) {
            float v = sc[ct][rb][r] * SCALE;
            if (maskt && kvc > qbase + rb * 16 + hq * 4 + r) v = -1.0e9f;
            sc[ct][rb][r] = v;
          }
      }

      float sf[2][4];
#pragma unroll
      for (int rb = 0; rb < 2; ++rb)
#pragma unroll
        for (int r = 0; r < 4; ++r) {
          float tmax = fmaxf(fmaxf(sc[0][rb][r], sc[1][rb][r]),
                             fmaxf(sc[2][rb][r], sc[3][rb][r]));
          tmax = fmaxf(tmax, __shfl_xor(tmax, 1));
          tmax = fmaxf(tmax, __shfl_xor(tmax, 2));
          tmax = fmaxf(tmax, __shfl_xor(tmax, 4));
          tmax = fmaxf(tmax, __shfl_xor(tmax, 8));
          float mn = fmaxf(m_run[rb][r], tmax);
          sf[rb][r] = __expf(m_run[rb][r] - mn);
          m_run[rb][r] = mn;
        }

#pragma unroll
      for (int rb = 0; rb < 2; ++rb)
#pragma unroll
        for (int r = 0; r < 4; ++r) {
          int prow = rb * 16 + hq * 4 + r;
          int swz = (prow & 7) << 4;
          float rsum = 0.f;
#pragma unroll
          for (int ct = 0; ct < 4; ++ct) {
            float pv = __expf(sc[ct][rb][r] - m_run[rb][r]);
            rsum += pv;
            *(unsigned short*)((char*)Pw + ((prow * 128 + (ct * 16 + np) * 2) ^ swz)) = f2bfu(pv);
          }
          rsum += __shfl_xor(rsum, 1);
          rsum += __shfl_xor(rsum, 2);
          rsum += __shfl_xor(rsum, 4);
          rsum += __shfl_xor(rsum, 8);
          l_run[rb][r] = l_run[rb][r] * sf[rb][r] + rsum;
        }

#pragma unroll
      for (int rb = 0; rb < 2; ++rb)
#pragma unroll
        for (int nt2 = 0; nt2 < 8; ++nt2)
#pragma unroll
          for (int r = 0; r < 4; ++r)
            acc[rb][nt2][r] *= sf[rb][r];

#pragma unroll
      for (int kb2 = 0; kb2 < 2; ++kb2) {
        bf16x8 pa0 = *(const bf16x8*)((char*)Pw +
            (((0 * 16 + np) * 128 + kb2 * 64 + hq * 16) ^ ((np & 7) << 4)));
        bf16x8 pa1 = *(const bf16x8*)((char*)Pw +
            (((1 * 16 + np) * 128 + kb2 * 64 + hq * 16) ^ ((np & 7) << 4)));
#pragma unroll
        for (int nt2 = 0; nt2 < 8; ++nt2) {
          int col = nt2 * 16 + np;
          bf16x8 vf = *(const bf16x8*)((char*)Vt +
              ((col * 128 + kb2 * 64 + hq * 16) ^ ((col & 7) << 4)));
          acc[0][nt2] = __builtin_amdgcn_mfma_f32_16x16x32_bf16(pa0, vf, acc[0][nt2], 0, 0, 0);
          acc[1][nt2] = __builtin_amdgcn_mfma_f32_16x16x32_bf16(pa1, vf, acc[1][nt2], 0, 0, 0);
        }
      }
    }

#pragma unroll
    for (int rb = 0; rb < 2; ++rb)
#pragma unroll
      for (int r = 0; r < 4; ++r) {
        float rl = 1.0f / l_run[rb][r];
        int orow = qbase + rb * 16 + hq * 4 + r;
#pragma unroll
        for (int nt2 = 0; nt2 < 8; ++nt2)
          Og[(size_t)orow * DIM + nt2 * 16 + np] = f2bfu(acc[rb][nt2][r] * rl);
      }
  }
}

extern "C" void kernel_launch(void* const* d_in, const int* in_sizes, int n_in,
                              void* d_out, int out_size, void* d_ws, size_t ws_size,
                              hipStream_t stream) {
  const float* x  = (const float*)d_in[0];
  const float* wq = (const float*)d_in[1];
  const float* bq = (const float*)d_in[2];
  const float* wk = (const float*)d_in[3];
  const float* bk = (const float*)d_in[4];
  const float* wv = (const float*)d_in[5];
  const float* bv = (const float*)d_in[6];
  const float* wo = (const float*)d_in[7];
  const float* bo = (const float*)d_in[8];
  float* out = (float*)d_out;

  char* ws = (char*)d_ws;
  unsigned short* wqkvb = (unsigned short*)(ws);                  // 96 MB [12288][4096]
  float* part           = (float*)(ws);                           // 64 MB (overlays wqkvb)
  unsigned short* wob   = (unsigned short*)(ws + (96ll  << 20));  // 32 MB
  unsigned short* xb    = (unsigned short*)(ws + (128ll << 20));  // 16 MB
  unsigned short* qkv   = (unsigned short*)(ws + (144ll << 20));  // 48 MB [2048][12288]
  unsigned short* ab    = (unsigned short*)(ws + (192ll << 20));  // 16 MB
  float* biasqkv = (float*)(ws + (208ll << 20));                  // 48 KB
  float* cosT    = (float*)(ws + (208ll << 20) + (64  << 10));    // 256 KB
  float* sinT    = (float*)(ws + (208ll << 20) + (320 << 10));    // 256 KB

  // fp32 -> bf16 (weights packed: wq|wk|wv contiguous rows)
  cvt_bf16_kernel<<<2048, 256, 0, stream>>>(x,  xb, (long)MROWS * DIM / 4);
  cvt_bf16_kernel<<<2048, 256, 0, stream>>>(wq, wqkvb,                        (long)DIM * DIM / 4);
  cvt_bf16_kernel<<<2048, 256, 0, stream>>>(wk, wqkvb + (size_t)DIM * DIM,    (long)DIM * DIM / 4);
  cvt_bf16_kernel<<<2048, 256, 0, stream>>>(wv, wqkvb + 2 * (size_t)DIM * DIM,(long)DIM * DIM / 4);
  cvt_bf16_kernel<<<2048, 256, 0, stream>>>(wo, wob, (long)DIM * DIM / 4);

  concat3_kernel<<<48, 256, 0, stream>>>(bq, bk, bv, biasqkv);
  rope_table_kernel<<<SEQ, 64, 0, stream>>>(cosT, sinT);

  // fused QKV GEMM (+bias +RoPE in epilogue): [2048,4096]x[12288,4096]^T
  dim3 gq(LDQ / 192, MROWS / 256, 1);  // (64, 8) = 512 blocks = 2 exact rounds
  gemm_q_kernel<unsigned short, true, 192><<<gq, 512, 0, stream>>>(
      xb, wqkvb, biasqkv, qkv, MROWS, LDQ, DIM, DIM, cosT, sinT);

  dim3 ga(4, BATCH * NH);  // 4 qtile-pairs x 64 heads
  flash_attn_kernel<<<ga, 256, 0, stream>>>(qkv, ab);

  // output GEMM, K-split x2 into fp32 partials (overlaying dead wqkvb region)
  dim3 go(DIM / 256, MROWS / 256, 2);  // (16, 8, 2) = 256 blocks = 1 exact round
  gemm_q_kernel<float, false, 256><<<go, 512, 0, stream>>>(
      ab, wob, nullptr, part, MROWS, DIM, DIM, DIM / 2, nullptr, nullptr);

  reduce_bias_kernel<<<(MROWS * DIM / 4 + 255) / 256, 256, 0, stream>>>(part, bo, out);
}